// Round 3
// baseline (133.911 us; speedup 1.0000x reference)
//
#include <hip/hip_runtime.h>
#include <hip/hip_bf16.h>

#define NR  8192      // rows per view
#define M   16384     // 2*NR concatenated
#define DIM 128
#define TILEB 32768   // 128 rows * 256 B (one Y col-tile)
#define NTILES 4160   // upper-triangular 256x128 tiles: sum_{r=0..63}(128-2r)
#define NBLK 512

constexpr float INV_T   = 2.5f;                  // 1/0.4
constexpr float SCALE_S = 1.89914134f;           // sqrt(2.5*log2(e)); s^2=2.5*log2e
constexpr float E_REFL  = 12.182493960703473f;   // exp(2.5)

typedef short short8 __attribute__((ext_vector_type(8)));
typedef float f32x4  __attribute__((ext_vector_type(4)));

typedef const __attribute__((address_space(1))) unsigned int* gas_u32;
typedef __attribute__((address_space(3))) unsigned int*       las_u32;

__device__ __forceinline__ unsigned short f2bf(float f) {
    __hip_bfloat16 h = __float2bfloat16(f);
    return *reinterpret_cast<unsigned short*>(&h);
}

__device__ __forceinline__ float fexp2(float x) {
#if __has_builtin(__builtin_amdgcn_exp2f)
    return __builtin_amdgcn_exp2f(x);
#else
    return exp2f(x);
#endif
}

// Stage one 128x128 bf16 tile (32 KB) global->LDS, 8 x global_load_lds(16B)
// per wave. LDS dest linear; global src XOR-pre-swizzled (involution on byte
// bits 4..6 keyed by row&7) so swizzled ds_read_b128 is low-conflict.
__device__ __forceinline__ void stage_tile(const char* __restrict__ gsrc,
                                           char* lds, int w, int lane) {
    #pragma unroll
    for (int it = 0; it < 8; ++it) {
        int off = w * 8192 + it * 1024 + lane * 16;
        int swz = off ^ (((off >> 8) & 7) << 4);
        __builtin_amdgcn_global_load_lds((gas_u32)(gsrc + swz),
                                         (las_u32)(lds + w * 8192 + it * 1024),
                                         16, 0, 0);
    }
}

// ---------------------------------------------------------------------------
// Kernel 1: L2-normalize rows; store bf16 Z = [z1n; z2n] PRE-SCALED by
// SCALE_S (MFMA output is then directly the exp2 argument); fp32 cross dot;
// zero the rowsum array R.
// ---------------------------------------------------------------------------
__global__ __launch_bounds__(256) void norm_kernel(
    const float* __restrict__ outp, const float* __restrict__ augp,
    unsigned short* __restrict__ Z, float* __restrict__ R,
    float* __restrict__ posdot)
{
    int gt = blockIdx.x * 256 + threadIdx.x;
    if (gt < M) R[gt] = 0.0f;

    const int w    = threadIdx.x >> 6;
    const int lane = threadIdx.x & 63;
    const int row  = blockIdx.x * 4 + w;

    float2 a = *(const float2*)(outp + row * DIM + lane * 2);
    float2 b = *(const float2*)(augp + row * DIM + lane * 2);

    float ssa = a.x * a.x + a.y * a.y;
    float ssb = b.x * b.x + b.y * b.y;
    #pragma unroll
    for (int m = 1; m < 64; m <<= 1) {
        ssa += __shfl_xor(ssa, m);
        ssb += __shfl_xor(ssb, m);
    }
    float inva = 1.0f / fmaxf(sqrtf(ssa), 1e-12f);
    float invb = 1.0f / fmaxf(sqrtf(ssb), 1e-12f);

    float xa0 = a.x * inva, xa1 = a.y * inva;
    float xb0 = b.x * invb, xb1 = b.y * invb;

    ushort2 s1; s1.x = f2bf(xa0 * SCALE_S); s1.y = f2bf(xa1 * SCALE_S);
    ushort2 s2; s2.x = f2bf(xb0 * SCALE_S); s2.y = f2bf(xb1 * SCALE_S);
    *(ushort2*)(Z + (size_t)row * DIM + lane * 2)        = s1;
    *(ushort2*)(Z + (size_t)(NR + row) * DIM + lane * 2) = s2;

    float d = xa0 * xb0 + xa1 * xb1;
    #pragma unroll
    for (int m = 1; m < 64; m <<= 1) d += __shfl_xor(d, m);
    if (lane == 0) posdot[row] = d;
}

// ---------------------------------------------------------------------------
// Kernel 2: symmetric Gram row-sums. E = exp2(Zs Zs^T) is symmetric; we walk
// only upper-triangular 256x128 tiles (tile (r,c) active iff c >= 2r).
//   d = c-2r == 0 : waves 0,1 hold the diagonal 128x128 square (rowsum only);
//                   waves 2,3 are below-diagonal (skip).
//   d == 1        : waves 0,1 strictly-upper (rowsum+colsum); waves 2,3 diag.
//   d >= 2        : all strictly-upper (rowsum+colsum).
// Block: 256 thr / 4 waves; wave owns 64 rows; A-frags global->registers
// (X never in LDS); Y-tiles double-buffered in LDS (64 KB -> 2 blocks/CU).
// Linearized triangle (row r has 128-2r tiles, S(r)=r*(129-r)) split into 512
// near-equal strips of 8-9 tiles.
// ---------------------------------------------------------------------------
__global__ __launch_bounds__(256, 2) void gram_kernel(
    const unsigned short* __restrict__ Z, float* __restrict__ R)
{
    __shared__ char buf[2][TILEB];   // 64 KB

    const int tid  = threadIdx.x;
    const int w    = tid >> 6;
    const int lane = tid & 63;
    const int l16  = lane & 15;
    const int lg   = lane >> 4;
    const int bid  = blockIdx.x;

    const int t0 = (bid * NTILES) >> 9;
    const int t1 = ((bid + 1) * NTILES) >> 9;

    // decode t0 -> (r, c)
    int r = (int)((129.0f - sqrtf(16641.0f - 4.0f * (float)t0)) * 0.5f);
    r = max(0, min(63, r));
    while (r * (129 - r) > t0) --r;
    while ((r + 1) * (128 - r) <= t0) ++r;   // S(r+1) = (r+1)*(128-r)
    int c = 2 * r + (t0 - r * (129 - r));

    const char* Zb = (const char*)Z;

    short8 afrag[4][4];
    auto loadA = [&](int rr) {
        #pragma unroll
        for (int rt = 0; rt < 4; ++rt)
            #pragma unroll
            for (int ks = 0; ks < 4; ++ks) {
                int row = rr * 256 + w * 64 + rt * 16 + l16;
                afrag[rt][ks] = *(const short8*)(Zb + row * 256 + ks * 64 + lg * 16);
            }
    };

    f32x4 rs[4];
    #pragma unroll
    for (int rt = 0; rt < 4; ++rt) rs[rt] = (f32x4){0.f, 0.f, 0.f, 0.f};

    auto flushR = [&](int rr) {
        #pragma unroll
        for (int rt = 0; rt < 4; ++rt)
            #pragma unroll
            for (int q = 0; q < 4; ++q) {
                float v = rs[rt][q];
                v += __shfl_xor(v, 1);  v += __shfl_xor(v, 2);
                v += __shfl_xor(v, 4);  v += __shfl_xor(v, 8);
                if (l16 == 0)
                    atomicAdd(&R[rr * 256 + w * 64 + rt * 16 + lg * 4 + q], v);
            }
    };

    loadA(r);
    stage_tile(Zb + (size_t)c * TILEB, buf[0], w, lane);
    __syncthreads();

    int par  = 0;
    int rcur = r;
    const f32x4 zero4 = (f32x4){0.f, 0.f, 0.f, 0.f};

    for (int t = t0; t < t1; ++t) {
        int rn = rcur, cn = c + 1;
        if (cn > 127) { rn = rcur + 1; cn = 2 * rn; }
        const bool haveNext = (t + 1 < t1);
        if (haveNext)
            stage_tile(Zb + (size_t)cn * TILEB, buf[par ^ 1], w, lane);

        const int  d      = c - 2 * rcur;
        const bool active = !(d == 0 && w >= 2);
        const bool docol  = (d >= 2) || (d == 1 && w < 2);

        if (active) {
            const char* cur = buf[par];
            f32x4 acc[4][8];
            #pragma unroll
            for (int ks = 0; ks < 4; ++ks) {
                #pragma unroll
                for (int ct = 0; ct < 8; ++ct) {
                    int rrow = ct * 16 + l16;
                    int off  = rrow * 256 + ks * 64 + lg * 16;
                    short8 bf = *(const short8*)(cur + (off ^ ((rrow & 7) << 4)));
                    #pragma unroll
                    for (int rt = 0; rt < 4; ++rt)
                        acc[rt][ct] = (ks == 0)
                            ? __builtin_amdgcn_mfma_f32_16x16x32_bf16(
                                  afrag[rt][0], bf, zero4, 0, 0, 0)
                            : __builtin_amdgcn_mfma_f32_16x16x32_bf16(
                                  afrag[rt][ks], bf, acc[rt][ct], 0, 0, 0);
                }
            }

            float csum[8];
            #pragma unroll
            for (int ct = 0; ct < 8; ++ct) csum[ct] = 0.f;

            #pragma unroll
            for (int rt = 0; rt < 4; ++rt)
                #pragma unroll
                for (int ct = 0; ct < 8; ++ct) {
                    f32x4 v = acc[rt][ct];
                    f32x4 e;
                    e[0] = fexp2(v[0]); e[1] = fexp2(v[1]);
                    e[2] = fexp2(v[2]); e[3] = fexp2(v[3]);
                    rs[rt] += e;
                    csum[ct] += (e[0] + e[1]) + (e[2] + e[3]);
                }

            if (docol) {
                #pragma unroll
                for (int ct = 0; ct < 8; ++ct) {
                    float v = csum[ct];
                    v += __shfl_xor(v, 16); v += __shfl_xor(v, 32);
                    if (lg == 0)
                        atomicAdd(&R[c * 128 + ct * 16 + l16], v);
                }
            }
        }

        __syncthreads();
        if (haveNext) {
            if (rn != rcur) {
                flushR(rcur);
                #pragma unroll
                for (int rt = 0; rt < 4; ++rt) rs[rt] = (f32x4){0.f,0.f,0.f,0.f};
                loadA(rn);
                rcur = rn;
            }
            c = cn;
            par ^= 1;
        }
    }
    flushR(rcur);
}

// ---------------------------------------------------------------------------
// Kernel 3: loss = mean_i [ -dot_i/tau + 0.5(log(R_i - E) + log(R_{NR+i} - E)) ]
// ---------------------------------------------------------------------------
__global__ __launch_bounds__(256) void final_kernel(
    const float* __restrict__ R, const float* __restrict__ posdot,
    float* __restrict__ outv)
{
    float local = 0.0f;
    for (int i = threadIdx.x; i < NR; i += 256) {
        float d1 = R[i]      - E_REFL;
        float d2 = R[NR + i] - E_REFL;
        local += -posdot[i] * INV_T + 0.5f * (logf(d1) + logf(d2));
    }
    __shared__ float red[256];
    red[threadIdx.x] = local;
    __syncthreads();
    for (int s = 128; s > 0; s >>= 1) {
        if ((int)threadIdx.x < s) red[threadIdx.x] += red[threadIdx.x + s];
        __syncthreads();
    }
    if (threadIdx.x == 0) outv[0] = red[0] * (1.0f / NR);
}

// ---------------------------------------------------------------------------
extern "C" void kernel_launch(void* const* d_in, const int* in_sizes, int n_in,
                              void* d_out, int out_size, void* d_ws, size_t ws_size,
                              hipStream_t stream) {
    const float* outp = (const float*)d_in[0];
    const float* augp = (const float*)d_in[1];

    char* ws = (char*)d_ws;
    unsigned short* Z = (unsigned short*)ws;                  // 4 MB bf16 [16384][128]
    float* R      = (float*)(ws + 4194304);                   // 16384 f32 row sums
    float* posdot = (float*)(ws + 4194304 + 65536);           // 8192 f32
    float* outf   = (float*)d_out;

    hipLaunchKernelGGL(norm_kernel, dim3(2048), dim3(256), 0, stream,
                       outp, augp, Z, R, posdot);

    hipLaunchKernelGGL(gram_kernel, dim3(NBLK), dim3(256), 0, stream,
                       Z, R);

    hipLaunchKernelGGL(final_kernel, dim3(1), dim3(256), 0, stream,
                       R, posdot, outf);
}

// Round 4
// 120.573 us; speedup vs baseline: 1.1106x; 1.1106x over previous
//
#include <hip/hip_runtime.h>
#include <hip/hip_bf16.h>

#define NR  8192      // rows per view
#define M   16384     // 2*NR concatenated
#define DIM 128
#define TILEB 32768   // 128 rows * 256 B (one Y col-tile)

constexpr float INV_T   = 2.5f;                  // 1/0.4
constexpr float SCALE_S = 1.89914134f;           // sqrt(2.5*log2(e)); s^2=2.5*log2e
constexpr float E_REFL  = 12.182493960703473f;   // exp(2.5)

typedef short short8 __attribute__((ext_vector_type(8)));
typedef float f32x4  __attribute__((ext_vector_type(4)));

typedef const __attribute__((address_space(1))) unsigned int* gas_u32;
typedef __attribute__((address_space(3))) unsigned int*       las_u32;

__device__ __forceinline__ unsigned short f2bf(float f) {
    __hip_bfloat16 h = __float2bfloat16(f);
    return *reinterpret_cast<unsigned short*>(&h);
}

__device__ __forceinline__ float fexp2(float x) {
#if __has_builtin(__builtin_amdgcn_exp2f)
    return __builtin_amdgcn_exp2f(x);
#else
    return exp2f(x);
#endif
}

// Stage one 128x128 bf16 tile (32 KB) global->LDS, 8 x global_load_lds(16B)
// per wave. LDS dest linear; global src XOR-pre-swizzled (involution on byte
// bits 4..6 keyed by row&7) so swizzled ds_read_b128 is low-conflict.
__device__ __forceinline__ void stage_tile(const char* __restrict__ gsrc,
                                           char* lds, int w, int lane) {
    #pragma unroll
    for (int it = 0; it < 8; ++it) {
        int off = w * 8192 + it * 1024 + lane * 16;
        int swz = off ^ (((off >> 8) & 7) << 4);
        __builtin_amdgcn_global_load_lds((gas_u32)(gsrc + swz),
                                         (las_u32)(lds + w * 8192 + it * 1024),
                                         16, 0, 0);
    }
}

// ---------------------------------------------------------------------------
// Kernel 1: L2-normalize rows; store bf16 Z = [z1n; z2n] PRE-SCALED by
// SCALE_S (MFMA output is then directly the exp2 argument); fp32 cross dot;
// zero the rowsum array R.
// ---------------------------------------------------------------------------
__global__ __launch_bounds__(256) void norm_kernel(
    const float* __restrict__ outp, const float* __restrict__ augp,
    unsigned short* __restrict__ Z, float* __restrict__ R,
    float* __restrict__ posdot)
{
    int gt = blockIdx.x * 256 + threadIdx.x;
    if (gt < M) R[gt] = 0.0f;

    const int w    = threadIdx.x >> 6;
    const int lane = threadIdx.x & 63;
    const int row  = blockIdx.x * 4 + w;

    float2 a = *(const float2*)(outp + row * DIM + lane * 2);
    float2 b = *(const float2*)(augp + row * DIM + lane * 2);

    float ssa = a.x * a.x + a.y * a.y;
    float ssb = b.x * b.x + b.y * b.y;
    #pragma unroll
    for (int m = 1; m < 64; m <<= 1) {
        ssa += __shfl_xor(ssa, m);
        ssb += __shfl_xor(ssb, m);
    }
    float inva = 1.0f / fmaxf(sqrtf(ssa), 1e-12f);
    float invb = 1.0f / fmaxf(sqrtf(ssb), 1e-12f);

    float xa0 = a.x * inva, xa1 = a.y * inva;
    float xb0 = b.x * invb, xb1 = b.y * invb;

    ushort2 s1; s1.x = f2bf(xa0 * SCALE_S); s1.y = f2bf(xa1 * SCALE_S);
    ushort2 s2; s2.x = f2bf(xb0 * SCALE_S); s2.y = f2bf(xb1 * SCALE_S);
    *(ushort2*)(Z + (size_t)row * DIM + lane * 2)        = s1;
    *(ushort2*)(Z + (size_t)(NR + row) * DIM + lane * 2) = s2;

    float d = xa0 * xb0 + xa1 * xb1;
    #pragma unroll
    for (int m = 1; m < 64; m <<= 1) d += __shfl_xor(d, m);
    if (lane == 0) posdot[row] = d;
}

// ---------------------------------------------------------------------------
// Kernel 2: row sums of exp2(Zs Zs^T), full matrix, lockstep streaming.
// Grid (8 chunks, 64 row-blocks) = 512 blocks = 2/CU (64 KB LDS cap).
// Block owns 256 rows; wave owns 64 rows (afrag[4][4] in registers, loaded
// straight from global/L2 — A never touches LDS). Chunk = 16 Y col-tiles,
// staged double-buffered; all 64 blocks of a chunk read the same tile
// sequence (and land on the same XCD under %8 round-robin) -> L2-hot.
// Per tile per wave: 32 ds_read_b128 feed 128 MFMAs (4 rt x 8 ct x 4 ks).
// ---------------------------------------------------------------------------
__global__ __launch_bounds__(256, 2) void gram_kernel(
    const unsigned short* __restrict__ Z, float* __restrict__ R)
{
    __shared__ char buf[2][TILEB];   // 64 KB

    const int tid  = threadIdx.x;
    const int w    = tid >> 6;
    const int lane = tid & 63;
    const int l16  = lane & 15;
    const int lg   = lane >> 4;
    const int ch   = blockIdx.x;     // 0..7   (16 col-tiles each)
    const int bi   = blockIdx.y;     // 0..63  (256-row strip)

    const char* Zb = (const char*)Z;

    // A fragments: 64 rows per wave, 4 k-slices; direct from global (L2-hot)
    short8 afrag[4][4];
    #pragma unroll
    for (int rt = 0; rt < 4; ++rt)
        #pragma unroll
        for (int ks = 0; ks < 4; ++ks) {
            int row = bi * 256 + w * 64 + rt * 16 + l16;
            afrag[rt][ks] = *(const short8*)(Zb + (size_t)row * 256 + ks * 64 + lg * 16);
        }

    stage_tile(Zb + (size_t)(ch * 16) * TILEB, buf[0], w, lane);
    __syncthreads();

    f32x4 rs[4];
    #pragma unroll
    for (int rt = 0; rt < 4; ++rt) rs[rt] = (f32x4){0.f, 0.f, 0.f, 0.f};
    const f32x4 zero4 = (f32x4){0.f, 0.f, 0.f, 0.f};

    const int xorv = (l16 & 7) << 4;   // swizzle term is lane-constant

    for (int t = 0; t < 16; ++t) {
        const char* cur = buf[t & 1];
        char* nxt = (char*)buf[(t + 1) & 1];
        if (t + 1 < 16)
            stage_tile(Zb + (size_t)(ch * 16 + t + 1) * TILEB, nxt, w, lane);

        f32x4 acc[4][8];
        #pragma unroll
        for (int ks = 0; ks < 4; ++ks) {
            #pragma unroll
            for (int ct = 0; ct < 8; ++ct) {
                int off = (ct * 16 + l16) * 256 + ks * 64 + lg * 16;
                short8 bf = *(const short8*)(cur + (off ^ xorv));
                #pragma unroll
                for (int rt = 0; rt < 4; ++rt)
                    acc[rt][ct] = (ks == 0)
                        ? __builtin_amdgcn_mfma_f32_16x16x32_bf16(
                              afrag[rt][0], bf, zero4, 0, 0, 0)
                        : __builtin_amdgcn_mfma_f32_16x16x32_bf16(
                              afrag[rt][ks], bf, acc[rt][ct], 0, 0, 0);
            }
        }

        // rowsum += exp2(acc)  (MFMA output is already the exp2 argument)
        #pragma unroll
        for (int rt = 0; rt < 4; ++rt)
            #pragma unroll
            for (int ct = 0; ct < 8; ++ct) {
                f32x4 v = acc[rt][ct];
                f32x4 e;
                e[0] = fexp2(v[0]); e[1] = fexp2(v[1]);
                e[2] = fexp2(v[2]); e[3] = fexp2(v[3]);
                rs[rt] += e;
            }

        __syncthreads();   // stage(t+1) complete + all waves done with cur
    }

    // reduce row sums across the 16 lanes holding one row's columns
    #pragma unroll
    for (int rt = 0; rt < 4; ++rt)
        #pragma unroll
        for (int q = 0; q < 4; ++q) {
            float v = rs[rt][q];
            v += __shfl_xor(v, 1);  v += __shfl_xor(v, 2);
            v += __shfl_xor(v, 4);  v += __shfl_xor(v, 8);
            if (l16 == 0)
                atomicAdd(&R[bi * 256 + w * 64 + rt * 16 + lg * 4 + q], v);
        }
}

// ---------------------------------------------------------------------------
// Kernel 3: loss = mean_i [ -dot_i/tau + 0.5(log(R_i - E) + log(R_{NR+i} - E)) ]
// ---------------------------------------------------------------------------
__global__ __launch_bounds__(256) void final_kernel(
    const float* __restrict__ R, const float* __restrict__ posdot,
    float* __restrict__ outv)
{
    float local = 0.0f;
    for (int i = threadIdx.x; i < NR; i += 256) {
        float d1 = R[i]      - E_REFL;
        float d2 = R[NR + i] - E_REFL;
        local += -posdot[i] * INV_T + 0.5f * (logf(d1) + logf(d2));
    }
    __shared__ float red[256];
    red[threadIdx.x] = local;
    __syncthreads();
    for (int s = 128; s > 0; s >>= 1) {
        if ((int)threadIdx.x < s) red[threadIdx.x] += red[threadIdx.x + s];
        __syncthreads();
    }
    if (threadIdx.x == 0) outv[0] = red[0] * (1.0f / NR);
}

// ---------------------------------------------------------------------------
extern "C" void kernel_launch(void* const* d_in, const int* in_sizes, int n_in,
                              void* d_out, int out_size, void* d_ws, size_t ws_size,
                              hipStream_t stream) {
    const float* outp = (const float*)d_in[0];
    const float* augp = (const float*)d_in[1];

    char* ws = (char*)d_ws;
    unsigned short* Z = (unsigned short*)ws;                  // 4 MB bf16 [16384][128]
    float* R      = (float*)(ws + 4194304);                   // 16384 f32 row sums
    float* posdot = (float*)(ws + 4194304 + 65536);           // 8192 f32
    float* outf   = (float*)d_out;

    hipLaunchKernelGGL(norm_kernel, dim3(2048), dim3(256), 0, stream,
                       outp, augp, Z, R, posdot);

    hipLaunchKernelGGL(gram_kernel, dim3(8, 64), dim3(256), 0, stream,
                       Z, R);

    hipLaunchKernelGGL(final_kernel, dim3(1), dim3(256), 0, stream,
                       R, posdot, outf);
}

// Round 5
// 120.249 us; speedup vs baseline: 1.1136x; 1.0027x over previous
//
#include <hip/hip_runtime.h>
#include <hip/hip_bf16.h>

#define NR  8192      // rows per view
#define M   16384     // 2*NR concatenated
#define DIM 128
#define TILEB 32768   // 128 rows * 256 B (one Y col-tile)

constexpr float INV_T   = 2.5f;                  // 1/0.4
constexpr float SCALE_S = 1.89914134f;           // sqrt(2.5*log2(e)); s^2=2.5*log2e
constexpr float E_REFL  = 12.182493960703473f;   // exp(2.5)

typedef short short8 __attribute__((ext_vector_type(8)));
typedef float f32x4  __attribute__((ext_vector_type(4)));

typedef const __attribute__((address_space(1))) unsigned int* gas_u32;
typedef __attribute__((address_space(3))) unsigned int*       las_u32;

__device__ __forceinline__ unsigned short f2bf(float f) {
    __hip_bfloat16 h = __float2bfloat16(f);
    return *reinterpret_cast<unsigned short*>(&h);
}

__device__ __forceinline__ float fexp2(float x) {
#if __has_builtin(__builtin_amdgcn_exp2f)
    return __builtin_amdgcn_exp2f(x);
#else
    return exp2f(x);
#endif
}

// Stage one 128x128 bf16 tile (32 KB) global->LDS with a 512-thread block:
// 4 x global_load_lds(16B) per wave. LDS dest linear; global src XOR-pre-
// swizzled (involution on byte bits 4..6 keyed by row&7) so swizzled
// ds_read_b128 fragment reads are low-conflict.
__device__ __forceinline__ void stage_tile512(const char* __restrict__ gsrc,
                                              char* lds, int w, int lane) {
    #pragma unroll
    for (int it = 0; it < 4; ++it) {
        int off = w * 4096 + it * 1024 + lane * 16;
        int swz = off ^ (((off >> 8) & 7) << 4);
        __builtin_amdgcn_global_load_lds((gas_u32)(gsrc + swz),
                                         (las_u32)(lds + w * 4096 + it * 1024),
                                         16, 0, 0);
    }
}

// ---------------------------------------------------------------------------
// Kernel 1: L2-normalize rows; store bf16 Z = [z1n; z2n] PRE-SCALED by
// SCALE_S (MFMA output is then directly the exp2 argument); fp32 cross dot;
// zero the rowsum array R.
// ---------------------------------------------------------------------------
__global__ __launch_bounds__(256) void norm_kernel(
    const float* __restrict__ outp, const float* __restrict__ augp,
    unsigned short* __restrict__ Z, float* __restrict__ R,
    float* __restrict__ posdot)
{
    int gt = blockIdx.x * 256 + threadIdx.x;
    if (gt < M) R[gt] = 0.0f;

    const int w    = threadIdx.x >> 6;
    const int lane = threadIdx.x & 63;
    const int row  = blockIdx.x * 4 + w;

    float2 a = *(const float2*)(outp + row * DIM + lane * 2);
    float2 b = *(const float2*)(augp + row * DIM + lane * 2);

    float ssa = a.x * a.x + a.y * a.y;
    float ssb = b.x * b.x + b.y * b.y;
    #pragma unroll
    for (int m = 1; m < 64; m <<= 1) {
        ssa += __shfl_xor(ssa, m);
        ssb += __shfl_xor(ssb, m);
    }
    float inva = 1.0f / fmaxf(sqrtf(ssa), 1e-12f);
    float invb = 1.0f / fmaxf(sqrtf(ssb), 1e-12f);

    float xa0 = a.x * inva, xa1 = a.y * inva;
    float xb0 = b.x * invb, xb1 = b.y * invb;

    ushort2 s1; s1.x = f2bf(xa0 * SCALE_S); s1.y = f2bf(xa1 * SCALE_S);
    ushort2 s2; s2.x = f2bf(xb0 * SCALE_S); s2.y = f2bf(xb1 * SCALE_S);
    *(ushort2*)(Z + (size_t)row * DIM + lane * 2)        = s1;
    *(ushort2*)(Z + (size_t)(NR + row) * DIM + lane * 2) = s2;

    float d = xa0 * xb0 + xa1 * xb1;
    #pragma unroll
    for (int m = 1; m < 64; m <<= 1) d += __shfl_xor(d, m);
    if (lane == 0) posdot[row] = d;
}

// ---------------------------------------------------------------------------
// Kernel 2: row sums of exp2(Zs Zs^T), lockstep streaming, counted-vmcnt ring.
// Grid (8 chunks, 32 row-blocks) = 256 blocks = 1/CU. Block = 512 thr (8
// waves) owning 512 rows; wave owns 64 rows (afrag[4][4] in registers, direct
// from global — one-time). Y: 16 tiles/chunk streamed through a 3-buffer LDS
// ring (96 KB). Per tile: issue stage(t+2) (4 gload_lds/wave), compute tile t
// (32 ds_read_b128 + 128 MFMA + exp2 accumulate), then
// s_waitcnt vmcnt(4) lgkmcnt(0) + raw s_barrier — tile t+2 loads stay in
// flight ACROSS the barrier (T3/T4; never drain to 0 in the loop).
// All 8 waves share one Y-stream -> half the LDS reads per CU vs 2x256 blocks.
// XCD: linear id = ch + 8*bi -> id%8 = ch; chunk working set (512 KB) L2-hot.
// ---------------------------------------------------------------------------
__global__ __launch_bounds__(512, 2) void gram_kernel(
    const unsigned short* __restrict__ Z, float* __restrict__ R)
{
    __shared__ char buf[3][TILEB];   // 96 KB -> 1 block/CU

    const int tid  = threadIdx.x;
    const int w    = tid >> 6;       // 0..7
    const int lane = tid & 63;
    const int l16  = lane & 15;
    const int lg   = lane >> 4;
    const int ch   = blockIdx.x;     // 0..7   (16 col-tiles each)
    const int bi   = blockIdx.y;     // 0..31  (512-row strip)

    const char* Zb = (const char*)Z;

    // A fragments: 64 rows per wave, 4 k-slices; direct from global (one-time)
    short8 afrag[4][4];
    #pragma unroll
    for (int rt = 0; rt < 4; ++rt)
        #pragma unroll
        for (int ks = 0; ks < 4; ++ks) {
            int row = bi * 512 + w * 64 + rt * 16 + l16;
            afrag[rt][ks] = *(const short8*)(Zb + (size_t)row * 256 + ks * 64 + lg * 16);
        }

    // prologue: stage tiles 0 and 1
    stage_tile512(Zb + (size_t)(ch * 16 + 0) * TILEB, (char*)buf[0], w, lane);
    stage_tile512(Zb + (size_t)(ch * 16 + 1) * TILEB, (char*)buf[1], w, lane);
    // afrag(16) + t0(4) complete; t1(4) in flight
    asm volatile("s_waitcnt vmcnt(4)" ::: "memory");
    __builtin_amdgcn_sched_barrier(0);
    __builtin_amdgcn_s_barrier();

    f32x4 rs[4];
    #pragma unroll
    for (int rt = 0; rt < 4; ++rt) rs[rt] = (f32x4){0.f, 0.f, 0.f, 0.f};
    const f32x4 zero4 = (f32x4){0.f, 0.f, 0.f, 0.f};

    const int xorv = (l16 & 7) << 4;   // read-side swizzle (lane-constant)

    #pragma unroll 1
    for (int t = 0; t < 16; ++t) {
        // issue next-next tile stage FIRST (wrap keeps vmcnt math uniform;
        // wrapped buffers are never read again — write-after-consume safe)
        stage_tile512(Zb + (size_t)(ch * 16 + ((t + 2) & 15)) * TILEB,
                      (char*)buf[(t + 2) % 3], w, lane);

        const char* cur = (const char*)buf[t % 3];

        __builtin_amdgcn_s_setprio(1);
        f32x4 acc[4][8];
        #pragma unroll
        for (int ks = 0; ks < 4; ++ks) {
            #pragma unroll
            for (int ct = 0; ct < 8; ++ct) {
                int off = (ct * 16 + l16) * 256 + ks * 64 + lg * 16;
                short8 bf = *(const short8*)(cur + (off ^ xorv));
                #pragma unroll
                for (int rt = 0; rt < 4; ++rt)
                    acc[rt][ct] = (ks == 0)
                        ? __builtin_amdgcn_mfma_f32_16x16x32_bf16(
                              afrag[rt][0], bf, zero4, 0, 0, 0)
                        : __builtin_amdgcn_mfma_f32_16x16x32_bf16(
                              afrag[rt][ks], bf, acc[rt][ct], 0, 0, 0);
            }
        }
        __builtin_amdgcn_s_setprio(0);

        // rowsum += exp2(acc)  (MFMA output is already the exp2 argument)
        #pragma unroll
        for (int rt = 0; rt < 4; ++rt)
            #pragma unroll
            for (int ct = 0; ct < 8; ++ct) {
                f32x4 v = acc[rt][ct];
                f32x4 e;
                e[0] = fexp2(v[0]); e[1] = fexp2(v[1]);
                e[2] = fexp2(v[2]); e[3] = fexp2(v[3]);
                rs[rt] += e;
            }

        // wait tile t+1 staged (4 newest = t+2 stay in flight), sync waves.
        // lgkmcnt(0): my ds_reads drained before others overwrite (rule 18).
        asm volatile("s_waitcnt vmcnt(4) lgkmcnt(0)" ::: "memory");
        __builtin_amdgcn_sched_barrier(0);
        __builtin_amdgcn_s_barrier();
    }

    // reduce row sums across the 16 lanes holding one row's columns
    #pragma unroll
    for (int rt = 0; rt < 4; ++rt)
        #pragma unroll
        for (int q = 0; q < 4; ++q) {
            float v = rs[rt][q];
            v += __shfl_xor(v, 1);  v += __shfl_xor(v, 2);
            v += __shfl_xor(v, 4);  v += __shfl_xor(v, 8);
            if (l16 == 0)
                atomicAdd(&R[bi * 512 + w * 64 + rt * 16 + lg * 4 + q], v);
        }
}

// ---------------------------------------------------------------------------
// Kernel 3: loss = mean_i [ -dot_i/tau + 0.5(log(R_i - E) + log(R_{NR+i} - E)) ]
// ---------------------------------------------------------------------------
__global__ __launch_bounds__(256) void final_kernel(
    const float* __restrict__ R, const float* __restrict__ posdot,
    float* __restrict__ outv)
{
    float local = 0.0f;
    for (int i = threadIdx.x; i < NR; i += 256) {
        float d1 = R[i]      - E_REFL;
        float d2 = R[NR + i] - E_REFL;
        local += -posdot[i] * INV_T + 0.5f * (logf(d1) + logf(d2));
    }
    __shared__ float red[256];
    red[threadIdx.x] = local;
    __syncthreads();
    for (int s = 128; s > 0; s >>= 1) {
        if ((int)threadIdx.x < s) red[threadIdx.x] += red[threadIdx.x + s];
        __syncthreads();
    }
    if (threadIdx.x == 0) outv[0] = red[0] * (1.0f / NR);
}

// ---------------------------------------------------------------------------
extern "C" void kernel_launch(void* const* d_in, const int* in_sizes, int n_in,
                              void* d_out, int out_size, void* d_ws, size_t ws_size,
                              hipStream_t stream) {
    const float* outp = (const float*)d_in[0];
    const float* augp = (const float*)d_in[1];

    char* ws = (char*)d_ws;
    unsigned short* Z = (unsigned short*)ws;                  // 4 MB bf16 [16384][128]
    float* R      = (float*)(ws + 4194304);                   // 16384 f32 row sums
    float* posdot = (float*)(ws + 4194304 + 65536);           // 8192 f32
    float* outf   = (float*)d_out;

    hipLaunchKernelGGL(norm_kernel, dim3(2048), dim3(256), 0, stream,
                       outp, augp, Z, R, posdot);

    hipLaunchKernelGGL(gram_kernel, dim3(8, 32), dim3(512), 0, stream,
                       Z, R);

    hipLaunchKernelGGL(final_kernel, dim3(1), dim3(256), 0, stream,
                       R, posdot, outf);
}

// Round 6
// 87.211 us; speedup vs baseline: 1.5355x; 1.3788x over previous
//
#include <hip/hip_runtime.h>
#include <hip/hip_bf16.h>

#define NR  8192      // rows per view
#define M   16384     // 2*NR concatenated
#define DIM 128
#define SUBB 16384    // 64 rows * 256 B (one Y sub-tile)

constexpr float INV_T   = 2.5f;                  // 1/0.4
constexpr float SCALE_S = 1.89914134f;           // sqrt(2.5*log2(e)); s^2=2.5*log2e
constexpr float E_REFL  = 12.182493960703473f;   // exp(2.5)

typedef short short8 __attribute__((ext_vector_type(8)));
typedef float f32x4  __attribute__((ext_vector_type(4)));

typedef const __attribute__((address_space(1))) unsigned int* gas_u32;
typedef __attribute__((address_space(3))) unsigned int*       las_u32;

__device__ __forceinline__ unsigned short f2bf(float f) {
    __hip_bfloat16 h = __float2bfloat16(f);
    return *reinterpret_cast<unsigned short*>(&h);
}

__device__ __forceinline__ float fexp2(float x) {
#if __has_builtin(__builtin_amdgcn_exp2f)
    return __builtin_amdgcn_exp2f(x);
#else
    return exp2f(x);
#endif
}

// Stage one 64-row (16 KB) sub-tile global->LDS with 256 threads:
// 4 x global_load_lds(16B) per wave. LDS dest linear; global src XOR-pre-
// swizzled (involution on byte bits 4..6 keyed by row&7) so swizzled
// ds_read_b128 fragment reads are low-conflict.
__device__ __forceinline__ void stage_sub(const char* __restrict__ gsrc,
                                          char* lds, int w, int lane) {
    #pragma unroll
    for (int it = 0; it < 4; ++it) {
        int off = w * 4096 + it * 1024 + lane * 16;
        int swz = off ^ (((off >> 8) & 7) << 4);
        __builtin_amdgcn_global_load_lds((gas_u32)(gsrc + swz),
                                         (las_u32)(lds + w * 4096 + it * 1024),
                                         16, 0, 0);
    }
}

// ---------------------------------------------------------------------------
// Kernel 1: L2-normalize rows; store bf16 Z = [z1n; z2n] PRE-SCALED by
// SCALE_S (MFMA output is then directly the exp2 argument); fp32 cross dot;
// zero the rowsum array R.
// ---------------------------------------------------------------------------
__global__ __launch_bounds__(256) void norm_kernel(
    const float* __restrict__ outp, const float* __restrict__ augp,
    unsigned short* __restrict__ Z, float* __restrict__ R,
    float* __restrict__ posdot)
{
    int gt = blockIdx.x * 256 + threadIdx.x;
    if (gt < M) R[gt] = 0.0f;

    const int w    = threadIdx.x >> 6;
    const int lane = threadIdx.x & 63;
    const int row  = blockIdx.x * 4 + w;

    float2 a = *(const float2*)(outp + row * DIM + lane * 2);
    float2 b = *(const float2*)(augp + row * DIM + lane * 2);

    float ssa = a.x * a.x + a.y * a.y;
    float ssb = b.x * b.x + b.y * b.y;
    #pragma unroll
    for (int m = 1; m < 64; m <<= 1) {
        ssa += __shfl_xor(ssa, m);
        ssb += __shfl_xor(ssb, m);
    }
    float inva = 1.0f / fmaxf(sqrtf(ssa), 1e-12f);
    float invb = 1.0f / fmaxf(sqrtf(ssb), 1e-12f);

    float xa0 = a.x * inva, xa1 = a.y * inva;
    float xb0 = b.x * invb, xb1 = b.y * invb;

    ushort2 s1; s1.x = f2bf(xa0 * SCALE_S); s1.y = f2bf(xa1 * SCALE_S);
    ushort2 s2; s2.x = f2bf(xb0 * SCALE_S); s2.y = f2bf(xb1 * SCALE_S);
    *(ushort2*)(Z + (size_t)row * DIM + lane * 2)        = s1;
    *(ushort2*)(Z + (size_t)(NR + row) * DIM + lane * 2) = s2;

    float d = xa0 * xb0 + xa1 * xb1;
    #pragma unroll
    for (int m = 1; m < 64; m <<= 1) d += __shfl_xor(d, m);
    if (lane == 0) posdot[row] = d;
}

// ---------------------------------------------------------------------------
// Kernel 2: row sums of exp2(Zs Zs^T).  Grid (16 col-chunks, 64 row-blocks)
// = 1024 blocks; 3 resident/CU (VGPR-capped via launch_bounds(256,3); LDS
// 32 KB/block) = 12 waves/CU; independent blocks de-phase so MFMA/VALU/LDS
// pipes overlap.  Block = 256 thr / 4 waves owns 256 rows; wave owns 64 rows
// (afrag[4][4] in regs, staged via LDS quarters — coalesced, no FETCH burst).
// Y: 16 sub-tiles of 64 rows (16 KB), double-buffered.  Compute is per-ct:
// 4 ds_read_b128 -> 16 MFMA (rt x ks-chain) -> exp2+accumulate immediately,
// so each ct's exps overlap the next ct's MFMAs inside the wave.
// Per B-frag read: 4 MFMAs (rt=4) -> half the LDS traffic of rt=2.
// ---------------------------------------------------------------------------
__global__ __launch_bounds__(256, 3) void gram_kernel(
    const unsigned short* __restrict__ Z, float* __restrict__ R)
{
    __shared__ char buf[2][SUBB];   // 32 KB

    const int tid  = threadIdx.x;
    const int w    = tid >> 6;       // 0..3
    const int lane = tid & 63;
    const int l16  = lane & 15;
    const int lg   = lane >> 4;
    const int ch   = blockIdx.x;     // 0..15 (1024 cols = 16 sub-tiles)
    const int rb   = blockIdx.y;     // 0..63 (256-row strip)

    const char* Zb = (const char*)Z;
    const char* Xg = Zb + (size_t)rb * 65536;            // 256 rows
    const char* Yg = Zb + (size_t)ch * 262144;           // 1024 cols

    const int xorv = (l16 & 7) << 4;  // read-side swizzle (lane-constant)

    // ---- X prologue: stage 4 x 16KB quarters; wave w reads quarter w ----
    short8 afrag[4][4];
    stage_sub(Xg,            buf[0], w, lane);
    stage_sub(Xg + SUBB,     buf[1], w, lane);
    __syncthreads();
    if (w < 2) {
        const char* q = buf[w];
        #pragma unroll
        for (int rt = 0; rt < 4; ++rt)
            #pragma unroll
            for (int ks = 0; ks < 4; ++ks) {
                int off = (rt * 16 + l16) * 256 + ks * 64 + lg * 16;
                afrag[rt][ks] = *(const short8*)(q + (off ^ xorv));
            }
    }
    __syncthreads();
    stage_sub(Xg + 2 * SUBB, buf[0], w, lane);
    stage_sub(Xg + 3 * SUBB, buf[1], w, lane);
    __syncthreads();
    if (w >= 2) {
        const char* q = buf[w - 2];
        #pragma unroll
        for (int rt = 0; rt < 4; ++rt)
            #pragma unroll
            for (int ks = 0; ks < 4; ++ks) {
                int off = (rt * 16 + l16) * 256 + ks * 64 + lg * 16;
                afrag[rt][ks] = *(const short8*)(q + (off ^ xorv));
            }
    }
    __syncthreads();

    // ---- Y stream: 16 sub-tiles, double-buffered ----
    stage_sub(Yg, buf[0], w, lane);
    __syncthreads();

    f32x4 rs[4];
    #pragma unroll
    for (int rt = 0; rt < 4; ++rt) rs[rt] = (f32x4){0.f, 0.f, 0.f, 0.f};
    const f32x4 zero4 = (f32x4){0.f, 0.f, 0.f, 0.f};

    #pragma unroll 1
    for (int s = 0; s < 16; ++s) {
        if (s + 1 < 16)
            stage_sub(Yg + (size_t)(s + 1) * SUBB, buf[(s + 1) & 1], w, lane);

        const char* cur = buf[s & 1];

        #pragma unroll
        for (int ct = 0; ct < 4; ++ct) {
            short8 bf[4];
            #pragma unroll
            for (int ks = 0; ks < 4; ++ks) {
                int off = (ct * 16 + l16) * 256 + ks * 64 + lg * 16;
                bf[ks] = *(const short8*)(cur + (off ^ xorv));
            }
            #pragma unroll
            for (int rt = 0; rt < 4; ++rt) {
                f32x4 a;
                a = __builtin_amdgcn_mfma_f32_16x16x32_bf16(afrag[rt][0], bf[0], zero4, 0, 0, 0);
                a = __builtin_amdgcn_mfma_f32_16x16x32_bf16(afrag[rt][1], bf[1], a, 0, 0, 0);
                a = __builtin_amdgcn_mfma_f32_16x16x32_bf16(afrag[rt][2], bf[2], a, 0, 0, 0);
                a = __builtin_amdgcn_mfma_f32_16x16x32_bf16(afrag[rt][3], bf[3], a, 0, 0, 0);
                f32x4 e;
                e[0] = fexp2(a[0]); e[1] = fexp2(a[1]);
                e[2] = fexp2(a[2]); e[3] = fexp2(a[3]);
                rs[rt] += e;
            }
        }
        __syncthreads();
    }

    // reduce row sums across the 16 lanes holding one row's columns
    #pragma unroll
    for (int rt = 0; rt < 4; ++rt)
        #pragma unroll
        for (int q = 0; q < 4; ++q) {
            float v = rs[rt][q];
            v += __shfl_xor(v, 1);  v += __shfl_xor(v, 2);
            v += __shfl_xor(v, 4);  v += __shfl_xor(v, 8);
            if (l16 == 0)
                atomicAdd(&R[rb * 256 + w * 64 + rt * 16 + lg * 4 + q], v);
        }
}

// ---------------------------------------------------------------------------
// Kernel 3: loss = mean_i [ -dot_i/tau + 0.5(log(R_i - E) + log(R_{NR+i} - E)) ]
// ---------------------------------------------------------------------------
__global__ __launch_bounds__(256) void final_kernel(
    const float* __restrict__ R, const float* __restrict__ posdot,
    float* __restrict__ outv)
{
    float local = 0.0f;
    for (int i = threadIdx.x; i < NR; i += 256) {
        float d1 = R[i]      - E_REFL;
        float d2 = R[NR + i] - E_REFL;
        local += -posdot[i] * INV_T + 0.5f * (logf(d1) + logf(d2));
    }
    __shared__ float red[256];
    red[threadIdx.x] = local;
    __syncthreads();
    for (int s = 128; s > 0; s >>= 1) {
        if ((int)threadIdx.x < s) red[threadIdx.x] += red[threadIdx.x + s];
        __syncthreads();
    }
    if (threadIdx.x == 0) outv[0] = red[0] * (1.0f / NR);
}

// ---------------------------------------------------------------------------
extern "C" void kernel_launch(void* const* d_in, const int* in_sizes, int n_in,
                              void* d_out, int out_size, void* d_ws, size_t ws_size,
                              hipStream_t stream) {
    const float* outp = (const float*)d_in[0];
    const float* augp = (const float*)d_in[1];

    char* ws = (char*)d_ws;
    unsigned short* Z = (unsigned short*)ws;                  // 4 MB bf16 [16384][128]
    float* R      = (float*)(ws + 4194304);                   // 16384 f32 row sums
    float* posdot = (float*)(ws + 4194304 + 65536);           // 8192 f32
    float* outf   = (float*)d_out;

    hipLaunchKernelGGL(norm_kernel, dim3(2048), dim3(256), 0, stream,
                       outp, augp, Z, R, posdot);

    hipLaunchKernelGGL(gram_kernel, dim3(16, 64), dim3(256), 0, stream,
                       Z, R);

    hipLaunchKernelGGL(final_kernel, dim3(1), dim3(256), 0, stream,
                       R, posdot, outf);
}

// Round 7
// 87.001 us; speedup vs baseline: 1.5392x; 1.0024x over previous
//
#include <hip/hip_runtime.h>
#include <hip/hip_bf16.h>

#define NR  8192      // rows per view
#define M   16384     // 2*NR concatenated
#define DIM 128
#define SUBB 16384    // 64 rows * 256 B (one Y sub-tile)

constexpr float INV_T   = 2.5f;                  // 1/0.4
constexpr float SCALE_S = 1.89914134f;           // sqrt(2.5*log2(e)); s^2=2.5*log2e
constexpr float E_REFL  = 12.182493960703473f;   // exp(2.5)

typedef short short8 __attribute__((ext_vector_type(8)));
typedef float f32x4  __attribute__((ext_vector_type(4)));

typedef const __attribute__((address_space(1))) unsigned int* gas_u32;
typedef __attribute__((address_space(3))) unsigned int*       las_u32;

__device__ __forceinline__ unsigned short f2bf(float f) {
    __hip_bfloat16 h = __float2bfloat16(f);
    return *reinterpret_cast<unsigned short*>(&h);
}

__device__ __forceinline__ float fexp2(float x) {
#if __has_builtin(__builtin_amdgcn_exp2f)
    return __builtin_amdgcn_exp2f(x);
#else
    return exp2f(x);
#endif
}

// Stage one 64-row (16 KB) sub-tile global->LDS with 256 threads:
// 4 x global_load_lds(16B) per wave. LDS dest linear; global src XOR-pre-
// swizzled (involution on byte bits 4..6 keyed by row&7) so swizzled
// ds_read_b128 fragment reads are low-conflict.
__device__ __forceinline__ void stage_sub(const char* __restrict__ gsrc,
                                          char* lds, int w, int lane) {
    #pragma unroll
    for (int it = 0; it < 4; ++it) {
        int off = w * 4096 + it * 1024 + lane * 16;
        int swz = off ^ (((off >> 8) & 7) << 4);
        __builtin_amdgcn_global_load_lds((gas_u32)(gsrc + swz),
                                         (las_u32)(lds + w * 4096 + it * 1024),
                                         16, 0, 0);
    }
}

// ---------------------------------------------------------------------------
// Kernel 1: L2-normalize rows; store bf16 Z = [z1n; z2n] PRE-SCALED by
// SCALE_S (MFMA output is then directly the exp2 argument); fp32 cross dot;
// zero the rowsum array R.
// ---------------------------------------------------------------------------
__global__ __launch_bounds__(256) void norm_kernel(
    const float* __restrict__ outp, const float* __restrict__ augp,
    unsigned short* __restrict__ Z, float* __restrict__ R,
    float* __restrict__ posdot)
{
    int gt = blockIdx.x * 256 + threadIdx.x;
    if (gt < M) R[gt] = 0.0f;

    const int w    = threadIdx.x >> 6;
    const int lane = threadIdx.x & 63;
    const int row  = blockIdx.x * 4 + w;

    float2 a = *(const float2*)(outp + row * DIM + lane * 2);
    float2 b = *(const float2*)(augp + row * DIM + lane * 2);

    float ssa = a.x * a.x + a.y * a.y;
    float ssb = b.x * b.x + b.y * b.y;
    #pragma unroll
    for (int m = 1; m < 64; m <<= 1) {
        ssa += __shfl_xor(ssa, m);
        ssb += __shfl_xor(ssb, m);
    }
    float inva = 1.0f / fmaxf(sqrtf(ssa), 1e-12f);
    float invb = 1.0f / fmaxf(sqrtf(ssb), 1e-12f);

    float xa0 = a.x * inva, xa1 = a.y * inva;
    float xb0 = b.x * invb, xb1 = b.y * invb;

    ushort2 s1; s1.x = f2bf(xa0 * SCALE_S); s1.y = f2bf(xa1 * SCALE_S);
    ushort2 s2; s2.x = f2bf(xb0 * SCALE_S); s2.y = f2bf(xb1 * SCALE_S);
    *(ushort2*)(Z + (size_t)row * DIM + lane * 2)        = s1;
    *(ushort2*)(Z + (size_t)(NR + row) * DIM + lane * 2) = s2;

    float d = xa0 * xb0 + xa1 * xb1;
    #pragma unroll
    for (int m = 1; m < 64; m <<= 1) d += __shfl_xor(d, m);
    if (lane == 0) posdot[row] = d;
}

// ---------------------------------------------------------------------------
// Kernel 2: row sums of exp2(Zs Zs^T).  R6 structure (grid 16x64, 256-thr
// block owns 256 rows, wave owns 64 rows, per-ct exp interleave) + T3/T4/T5:
// Y streamed through a 3 x 16KB LDS ring with UNIFORM wrapped staging and
// counted vmcnt — per sub-tile: issue stage(s+2) (4 gload_lds/wave), compute
// tile s, then s_waitcnt vmcnt(4) lgkmcnt(0) + raw s_barrier.  The newest 4
// loads (tile s+2) stay in flight ACROSS the barrier; never drained to 0 in
// the loop.  Wrapped staging at s=14,15 keeps the vmcnt arithmetic exact
// (vmcnt(4) always means "tile s+1 landed").  setprio(1) wraps the
// ds_read+MFMA cluster (T5).  LDS 48 KB -> 3 blocks/CU = 12 waves.
// ---------------------------------------------------------------------------
__global__ __launch_bounds__(256, 3) void gram_kernel(
    const unsigned short* __restrict__ Z, float* __restrict__ R)
{
    __shared__ char buf[3][SUBB];   // 48 KB ring

    const int tid  = threadIdx.x;
    const int w    = tid >> 6;       // 0..3
    const int lane = tid & 63;
    const int l16  = lane & 15;
    const int lg   = lane >> 4;
    const int ch   = blockIdx.x;     // 0..15 (1024 cols = 16 sub-tiles)
    const int rb   = blockIdx.y;     // 0..63 (256-row strip)

    const char* Zb = (const char*)Z;
    const char* Xg = Zb + (size_t)rb * 65536;            // 256 rows
    const char* Yg = Zb + (size_t)ch * 262144;           // 1024 cols

    const int xorv = (l16 & 7) << 4;  // read-side swizzle (lane-constant)

    // ---- X prologue: stage 4 x 16KB quarters; wave w reads quarter w ----
    short8 afrag[4][4];
    stage_sub(Xg,            buf[0], w, lane);
    stage_sub(Xg + SUBB,     buf[1], w, lane);
    __syncthreads();
    if (w < 2) {
        const char* q = buf[w];
        #pragma unroll
        for (int rt = 0; rt < 4; ++rt)
            #pragma unroll
            for (int ks = 0; ks < 4; ++ks) {
                int off = (rt * 16 + l16) * 256 + ks * 64 + lg * 16;
                afrag[rt][ks] = *(const short8*)(q + (off ^ xorv));
            }
    }
    __syncthreads();
    stage_sub(Xg + 2 * SUBB, buf[0], w, lane);
    stage_sub(Xg + 3 * SUBB, buf[1], w, lane);
    __syncthreads();
    if (w >= 2) {
        const char* q = buf[w - 2];
        #pragma unroll
        for (int rt = 0; rt < 4; ++rt)
            #pragma unroll
            for (int ks = 0; ks < 4; ++ks) {
                int off = (rt * 16 + l16) * 256 + ks * 64 + lg * 16;
                afrag[rt][ks] = *(const short8*)(q + (off ^ xorv));
            }
    }
    __syncthreads();   // all waves done reading X quarters

    // ---- Y prologue: stage tiles 0,1 into ring slots 0,1 ----
    char* p0 = (char*)buf[0];
    char* p1 = (char*)buf[1];
    char* p2 = (char*)buf[2];
    stage_sub(Yg,        p0, w, lane);
    stage_sub(Yg + SUBB, p1, w, lane);
    asm volatile("s_waitcnt vmcnt(4)" ::: "memory");   // tile 0 landed
    __builtin_amdgcn_sched_barrier(0);
    __builtin_amdgcn_s_barrier();

    f32x4 rs[4];
    #pragma unroll
    for (int rt = 0; rt < 4; ++rt) rs[rt] = (f32x4){0.f, 0.f, 0.f, 0.f};
    const f32x4 zero4 = (f32x4){0.f, 0.f, 0.f, 0.f};

    #pragma unroll 1
    for (int s = 0; s < 16; ++s) {
        // issue stage of tile (s+2) (wrapped; keeps vmcnt math uniform —
        // the overwritten slot was fully consumed before the last barrier)
        stage_sub(Yg + (size_t)((s + 2) & 15) * SUBB, p2, w, lane);

        __builtin_amdgcn_s_setprio(1);
        #pragma unroll
        for (int ct = 0; ct < 4; ++ct) {
            short8 bf[4];
            #pragma unroll
            for (int ks = 0; ks < 4; ++ks) {
                int off = (ct * 16 + l16) * 256 + ks * 64 + lg * 16;
                bf[ks] = *(const short8*)(p0 + (off ^ xorv));
            }
            #pragma unroll
            for (int rt = 0; rt < 4; ++rt) {
                f32x4 a;
                a = __builtin_amdgcn_mfma_f32_16x16x32_bf16(afrag[rt][0], bf[0], zero4, 0, 0, 0);
                a = __builtin_amdgcn_mfma_f32_16x16x32_bf16(afrag[rt][1], bf[1], a, 0, 0, 0);
                a = __builtin_amdgcn_mfma_f32_16x16x32_bf16(afrag[rt][2], bf[2], a, 0, 0, 0);
                a = __builtin_amdgcn_mfma_f32_16x16x32_bf16(afrag[rt][3], bf[3], a, 0, 0, 0);
                f32x4 e;
                e[0] = fexp2(a[0]); e[1] = fexp2(a[1]);
                e[2] = fexp2(a[2]); e[3] = fexp2(a[3]);
                rs[rt] += e;
            }
        }
        __builtin_amdgcn_s_setprio(0);

        // tile s+1 landed (newest 4 loads = tile s+2 stay in flight);
        // lgkmcnt(0): my ds_reads of p0 are drained before others overwrite.
        asm volatile("s_waitcnt vmcnt(4) lgkmcnt(0)" ::: "memory");
        __builtin_amdgcn_sched_barrier(0);
        __builtin_amdgcn_s_barrier();

        char* t = p0; p0 = p1; p1 = p2; p2 = t;   // rotate ring
    }

    // reduce row sums across the 16 lanes holding one row's columns
    #pragma unroll
    for (int rt = 0; rt < 4; ++rt)
        #pragma unroll
        for (int q = 0; q < 4; ++q) {
            float v = rs[rt][q];
            v += __shfl_xor(v, 1);  v += __shfl_xor(v, 2);
            v += __shfl_xor(v, 4);  v += __shfl_xor(v, 8);
            if (l16 == 0)
                atomicAdd(&R[rb * 256 + w * 64 + rt * 16 + lg * 4 + q], v);
        }
}

// ---------------------------------------------------------------------------
// Kernel 3: loss = mean_i [ -dot_i/tau + 0.5(log(R_i - E) + log(R_{NR+i} - E)) ]
// ---------------------------------------------------------------------------
__global__ __launch_bounds__(256) void final_kernel(
    const float* __restrict__ R, const float* __restrict__ posdot,
    float* __restrict__ outv)
{
    float local = 0.0f;
    for (int i = threadIdx.x; i < NR; i += 256) {
        float d1 = R[i]      - E_REFL;
        float d2 = R[NR + i] - E_REFL;
        local += -posdot[i] * INV_T + 0.5f * (logf(d1) + logf(d2));
    }
    __shared__ float red[256];
    red[threadIdx.x] = local;
    __syncthreads();
    for (int s = 128; s > 0; s >>= 1) {
        if ((int)threadIdx.x < s) red[threadIdx.x] += red[threadIdx.x + s];
        __syncthreads();
    }
    if (threadIdx.x == 0) outv[0] = red[0] * (1.0f / NR);
}

// ---------------------------------------------------------------------------
extern "C" void kernel_launch(void* const* d_in, const int* in_sizes, int n_in,
                              void* d_out, int out_size, void* d_ws, size_t ws_size,
                              hipStream_t stream) {
    const float* outp = (const float*)d_in[0];
    const float* augp = (const float*)d_in[1];

    char* ws = (char*)d_ws;
    unsigned short* Z = (unsigned short*)ws;                  // 4 MB bf16 [16384][128]
    float* R      = (float*)(ws + 4194304);                   // 16384 f32 row sums
    float* posdot = (float*)(ws + 4194304 + 65536);           // 8192 f32
    float* outf   = (float*)d_out;

    hipLaunchKernelGGL(norm_kernel, dim3(2048), dim3(256), 0, stream,
                       outp, augp, Z, R, posdot);

    hipLaunchKernelGGL(gram_kernel, dim3(16, 64), dim3(256), 0, stream,
                       Z, R);

    hipLaunchKernelGGL(final_kernel, dim3(1), dim3(256), 0, stream,
                       R, posdot, outf);
}